// Round 1
// baseline (314.017 us; speedup 1.0000x reference)
//
#include <hip/hip_runtime.h>
#include <stdint.h>

// ---------------------------------------------------------------------------
// PDG2Seq_GCN: B=16, N=1024, C=O=64, D=10, CHEB_K=2 (K=5 stacked terms)
// Plan:
//   K0a transpose_x : x[b][m][c] f32 -> XT0[b][c][m] bf16          (2 MB)
//   K0b transpose_wp: wp[d][ki][o]  -> wpT[d][o][ki] f32           (0.8 MB)
//   K4  wgen        : WT[n][o][ki] bf16 = sum_d emb[n,d] wpT[d]    (40 MB)
//   K2  hop1        : X1[s] = A_s @ x      (MFMA bf16, no-LDS K-loop)
//   K3  hop2        : X2[s] = A_s @ X1[s]
//   K5  final       : out[b,n,o] = Xg[16x320] @ W_n[320x64] + bias (MFMA)
// ---------------------------------------------------------------------------

typedef __attribute__((ext_vector_type(4))) float f32x4;
typedef __attribute__((ext_vector_type(2))) float f32x2;
typedef __attribute__((ext_vector_type(8))) short s16x8;
typedef __attribute__((ext_vector_type(8))) __bf16 bf16x8;

__device__ __forceinline__ unsigned short f2bf(float f) {
  union { float f; uint32_t u; } v; v.f = f;
  uint32_t r = v.u + 0x7FFFu + ((v.u >> 16) & 1u);   // RNE
  return (unsigned short)(r >> 16);
}
__device__ __forceinline__ uint32_t pack2(float a, float b) {
  return (uint32_t)f2bf(a) | ((uint32_t)f2bf(b) << 16);
}

union FragU { s16x8 s; bf16x8 b; };

// ---------------------------------------------------------------------------
// K0a: x [16][1024][64] f32  ->  XT0 [16][64][1024] bf16
// grid (16 n-tiles, 16 b), block 256
// ---------------------------------------------------------------------------
__global__ void transpose_x(const float* __restrict__ x,
                            unsigned short* __restrict__ XT0) {
  __shared__ unsigned short tl[64][72];
  const int b = blockIdx.y, n0 = blockIdx.x * 64;
  const int tid = threadIdx.x;
  {
    const int c4 = (tid & 15) * 4;
#pragma unroll
    for (int i = 0; i < 4; ++i) {
      const int row = (tid >> 4) + i * 16;
      f32x4 v = *(const f32x4*)(x + ((size_t)(b * 1024 + n0 + row)) * 64 + c4);
      *(uint32_t*)&tl[row][c4]     = pack2(v[0], v[1]);
      *(uint32_t*)&tl[row][c4 + 2] = pack2(v[2], v[3]);
    }
  }
  __syncthreads();
  {
    const int c = tid >> 2;
    const int nch = (tid & 3) * 16;
    s16x8 s0, s1;
#pragma unroll
    for (int j = 0; j < 8; ++j) {
      s0[j] = (short)tl[nch + j][c];
      s1[j] = (short)tl[nch + 8 + j][c];
    }
    unsigned short* p = XT0 + (size_t)(b * 64 + c) * 1024 + n0 + nch;
    *(s16x8*)p = s0;
    *(s16x8*)(p + 8) = s1;
  }
}

// ---------------------------------------------------------------------------
// K0b: wp [10][320][64] -> wpT [10][64][320] f32
// grid (5 ki-tiles, 10 d), block 256
// ---------------------------------------------------------------------------
__global__ void transpose_wp(const float* __restrict__ wp,
                             float* __restrict__ wpT) {
  __shared__ float tl[64][65];
  const int d = blockIdx.y;
  const int ki0 = blockIdx.x * 64;
  const int tid = threadIdx.x;
  const float* src = wp + (size_t)d * 20480;
  {
    const int o4 = (tid & 15) * 4;
#pragma unroll
    for (int i = 0; i < 4; ++i) {
      const int row = (tid >> 4) + i * 16;
      f32x4 v = *(const f32x4*)(src + (size_t)(ki0 + row) * 64 + o4);
      tl[row][o4] = v[0]; tl[row][o4 + 1] = v[1];
      tl[row][o4 + 2] = v[2]; tl[row][o4 + 3] = v[3];
    }
  }
  __syncthreads();
  {
    const int o = tid >> 2;
    const int kch = (tid & 3) * 16;
    float* dst = wpT + (size_t)d * 20480 + (size_t)o * 320 + ki0 + kch;
#pragma unroll
    for (int u = 0; u < 4; ++u) {
      f32x4 v = { tl[kch + 4 * u][o], tl[kch + 4 * u + 1][o],
                  tl[kch + 4 * u + 2][o], tl[kch + 4 * u + 3][o] };
      *(f32x4*)(dst + 4 * u) = v;
    }
  }
}

// ---------------------------------------------------------------------------
// K4: WT[n][o][ki] bf16 = sum_d emb[n,d] * wpT[d][o][ki]
// grid (80, 64 node-groups of 16), block 256. emb reads are wave-uniform
// (blockIdx-derived) -> scalar loads; 16 accumulators amortize wp reads.
// ---------------------------------------------------------------------------
__global__ __launch_bounds__(256) void wgen(const float* __restrict__ wpT,
                                            const float* __restrict__ emb,
                                            unsigned short* __restrict__ WT) {
  const int idx = blockIdx.x * 256 + threadIdx.x;   // o*320+ki, 0..20479
  const int n0 = blockIdx.y * 16;
  float wv[10];
#pragma unroll
  for (int d = 0; d < 10; ++d) wv[d] = wpT[(size_t)d * 20480 + idx];
#pragma unroll
  for (int g = 0; g < 16; ++g) {
    float a = 0.f;
#pragma unroll
    for (int d = 0; d < 10; ++d) a += emb[(n0 + g) * 10 + d] * wv[d];
    WT[(size_t)(n0 + g) * 20480 + idx] = f2bf(a);
  }
}

// ---------------------------------------------------------------------------
// K2/K3: hop GEMM. Per slice (s*16+b): out[1024][64] = A[1024][1024] @ X[1024][64]
// A-fragments straight from global fp32 (16 rows x 128 B contiguous per row),
// B-fragments 16 B bf16 loads from XT (k-contiguous). Depth-4 register
// pipeline, no barrier in K-loop. Epilogue: LDS transpose -> coalesced
// fp32 X-out + bf16 XT-out.
// grid (16 row-tiles, 32 slices), block 256 (4 waves x 16 rows x 64 cols)
// ---------------------------------------------------------------------------
#define PF 4
__global__ __launch_bounds__(256, 2) void hop_kernel(
    const float* __restrict__ adj, const unsigned short* __restrict__ XTin,
    float* __restrict__ Xout, unsigned short* __restrict__ XTout,
    int xt_shared, int write_xt) {
  const int slice = blockIdx.y;          // s*16 + b
  const int b = slice & 15;
  const float* __restrict__ A = adj + (size_t)slice * (1024u * 1024u);
  const unsigned short* __restrict__ XT =
      XTin + (size_t)(xt_shared ? b : slice) * (64 * 1024);
  const int tid = threadIdx.x;
  const int wave = tid >> 6, lane = tid & 63;
  const int l15 = lane & 15, q = lane >> 4;
  const int rowbase = blockIdx.x * 64;
  const int arow = rowbase + wave * 16 + l15;
  const float* __restrict__ aptr = A + (size_t)arow * 1024 + q * 8;
  const unsigned short* __restrict__ bptr = XT + (size_t)l15 * 1024 + q * 8;

  f32x4 acc[4];
#pragma unroll
  for (int t = 0; t < 4; ++t) acc[t] = (f32x4){0.f, 0.f, 0.f, 0.f};

  f32x4 araw[PF][2];
  s16x8 braw[PF][4];

  auto load_stage = [&](int j, int k0) {
    araw[j][0] = *(const f32x4*)(aptr + k0);
    araw[j][1] = *(const f32x4*)(aptr + k0 + 4);
#pragma unroll
    for (int t = 0; t < 4; ++t)
      braw[j][t] = *(const s16x8*)(bptr + (size_t)t * (16 * 1024) + k0);
  };

#pragma unroll
  for (int j = 0; j < PF - 1; ++j) load_stage(j, j * 32);

  for (int it0 = 0; it0 < 32; it0 += PF) {
#pragma unroll
    for (int jj = 0; jj < PF; ++jj) {
      const int i = it0 + jj;
      const int kpre = (i + PF - 1) * 32;
      if (kpre < 1024) load_stage((jj + PF - 1) & (PF - 1), kpre);
      FragU af;
#pragma unroll
      for (int e = 0; e < 4; ++e) {
        af.s[e]     = (short)f2bf(araw[jj][0][e]);
        af.s[e + 4] = (short)f2bf(araw[jj][1][e]);
      }
#pragma unroll
      for (int t = 0; t < 4; ++t) {
        FragU bf; bf.s = braw[jj][t];
        acc[t] = __builtin_amdgcn_mfma_f32_16x16x32_bf16(af.b, bf.b, acc[t],
                                                         0, 0, 0);
      }
    }
  }

  // Epilogue: transpose via LDS
  __shared__ float tile[64][65];
#pragma unroll
  for (int t = 0; t < 4; ++t)
#pragma unroll
    for (int r = 0; r < 4; ++r)
      tile[wave * 16 + q * 4 + r][t * 16 + l15] = acc[t][r];
  __syncthreads();

  {
    const int row = tid >> 2;
    const int cb = (tid & 3) * 16;
    float* __restrict__ outp = Xout + (size_t)slice * (1024 * 64) +
                               (size_t)(rowbase + row) * 64 + cb;
#pragma unroll
    for (int u = 0; u < 4; ++u) {
      f32x4 v = { tile[row][cb + 4 * u], tile[row][cb + 4 * u + 1],
                  tile[row][cb + 4 * u + 2], tile[row][cb + 4 * u + 3] };
      *(f32x4*)(outp + 4 * u) = v;
    }
  }
  if (write_xt) {
    const int c = tid >> 2;
    const int nch = (tid & 3) * 16;
    unsigned short* __restrict__ xtp = XTout + (size_t)slice * (64 * 1024) +
                                       (size_t)c * 1024 + rowbase + nch;
    s16x8 s0, s1;
#pragma unroll
    for (int j = 0; j < 8; ++j) {
      s0[j] = (short)f2bf(tile[nch + j][c]);
      s1[j] = (short)f2bf(tile[nch + 8 + j][c]);
    }
    *(s16x8*)xtp = s0;
    *(s16x8*)(xtp + 8) = s1;
  }
}

// ---------------------------------------------------------------------------
// K5: out[b,n,o] = Xg[b,n,:] (320) @ W_n[320,64] + bias[n,o]
// One wave per node: D[16b x 64o] via 4 o-tiles x 10 k-steps of 16x16x32.
// Xg staged bf16 in LDS (row stride 328 -> balanced banks, 16B aligned).
// grid 256 (4 nodes/block), block 256
// ---------------------------------------------------------------------------
__global__ __launch_bounds__(256, 2) void final_kernel(
    const float* __restrict__ x, const float* __restrict__ X1,
    const float* __restrict__ X2, const unsigned short* __restrict__ WT,
    const float* __restrict__ emb, const float* __restrict__ bias_pool,
    float* __restrict__ out) {
  __shared__ unsigned short xg[4][16][328];
  const int tid = threadIdx.x;
  const int node_base = blockIdx.x * 4;

  // stage x_g (k order: x, A0x, A0^2x, A1x, A1^2x) as bf16
  for (int u = tid; u < 10240; u += 256) {       // units of 2 ki
    const int nd = u / 2560;
    int rem = u - nd * 2560;
    const int bb = rem / 160;
    const int kiu = rem - bb * 160;
    const int ki = kiu * 2;
    const int k = ki >> 6;
    const int c = ki & 63;
    const int nn = node_base + nd;
    const float* src;
    if (k == 0) {
      src = x + ((size_t)bb * 1024 + nn) * 64 + c;
    } else {
      const float* arr = (k == 1 || k == 3) ? X1 : X2;
      const int s = (k >= 3) ? 1 : 0;
      src = arr + ((size_t)(s * 16 + bb) * 1024 + nn) * 64 + c;
    }
    f32x2 v = *(const f32x2*)src;
    *(uint32_t*)&xg[nd][bb][ki] = pack2(v[0], v[1]);
  }
  __syncthreads();

  const int wave = tid >> 6, lane = tid & 63;
  const int l15 = lane & 15, q = lane >> 4;
  const int n = node_base + wave;
  f32x4 acc[4];
#pragma unroll
  for (int t = 0; t < 4; ++t) acc[t] = (f32x4){0.f, 0.f, 0.f, 0.f};

  const unsigned short* wt0 =
      WT + (size_t)n * 20480 + (size_t)l15 * 320 + q * 8;
#pragma unroll
  for (int ks = 0; ks < 10; ++ks) {
    const int k0 = ks * 32;
    FragU af;
    af.s = *(const s16x8*)&xg[wave][l15][k0 + q * 8];
#pragma unroll
    for (int t = 0; t < 4; ++t) {
      FragU bf;
      bf.s = *(const s16x8*)(wt0 + (size_t)t * (16 * 320) + k0);
      acc[t] = __builtin_amdgcn_mfma_f32_16x16x32_bf16(af.b, bf.b, acc[t],
                                                       0, 0, 0);
    }
  }

#pragma unroll
  for (int t = 0; t < 4; ++t) {
    const int o = t * 16 + l15;
    float bv = 0.f;
#pragma unroll
    for (int d = 0; d < 10; ++d)
      bv += emb[n * 10 + d] * bias_pool[d * 64 + o];
#pragma unroll
    for (int r = 0; r < 4; ++r) {
      const int bb = q * 4 + r;
      out[((size_t)bb * 1024 + n) * 64 + o] = acc[t][r] + bv;
    }
  }
}

// ---------------------------------------------------------------------------
extern "C" void kernel_launch(void* const* d_in, const int* in_sizes, int n_in,
                              void* d_out, int out_size, void* d_ws,
                              size_t ws_size, hipStream_t stream) {
  const float* x   = (const float*)d_in[0];   // [16,1024,64]
  const float* adj = (const float*)d_in[1];   // [2,16,1024,1024]
  const float* emb = (const float*)d_in[2];   // [1024,10]
  const float* wp  = (const float*)d_in[3];   // [10,5,64,64]
  const float* bp  = (const float*)d_in[4];   // [10,64]
  float* out = (float*)d_out;                 // [16,1024,64]

  char* ws = (char*)d_ws;
  unsigned short* XT0 = (unsigned short*)(ws);                    // 2 MB
  unsigned short* XT1 = (unsigned short*)(ws + ((size_t)2 << 20)); // 4 MB
  float* X1  = (float*)(ws + ((size_t)6 << 20));                   // 8 MB
  float* X2  = (float*)(ws + ((size_t)14 << 20));                  // 8 MB
  float* wpT = (float*)(ws + ((size_t)22 << 20));                  // 0.82 MB
  unsigned short* WT = (unsigned short*)(ws + ((size_t)23 << 20)); // 40 MB

  transpose_x<<<dim3(16, 16), dim3(256), 0, stream>>>(x, XT0);
  transpose_wp<<<dim3(5, 10), dim3(256), 0, stream>>>(wp, wpT);
  wgen<<<dim3(80, 64), dim3(256), 0, stream>>>(wpT, emb, WT);
  hop_kernel<<<dim3(16, 32), dim3(256), 0, stream>>>(adj, XT0, X1, XT1, 1, 1);
  hop_kernel<<<dim3(16, 32), dim3(256), 0, stream>>>(adj, XT1, X2,
                                                     (unsigned short*)nullptr,
                                                     0, 0);
  final_kernel<<<dim3(256), dim3(256), 0, stream>>>(x, X1, X2, WT, emb, bp,
                                                    out);
}

// Round 2
// 279.082 us; speedup vs baseline: 1.1252x; 1.1252x over previous
//
#include <hip/hip_runtime.h>
#include <stdint.h>

// ---------------------------------------------------------------------------
// PDG2Seq_GCN: B=16, N=1024, C=O=64, D=10, CHEB_K=2 (K=5 stacked terms)
//   K0a transpose_x : x[b][m][c] f32 -> XT0[b][c][m] bf16          (2 MB)
//   K0b transpose_wp: wp[d][ki][o]  -> wpT[d][o][ki] f32           (0.8 MB)
//   K4  wgen        : WT[n][o][ki] bf16 = sum_d emb[n,d] wpT[d]    (40 MB)
//   K2  hop1        : X1[s] = A_s @ x    (MFMA bf16, global_load_lds dbuf)
//   K3  hop2        : X2[s] = A_s @ X1[s]
//   K5  final       : out[b,n,o] = Xg[16x320] @ W_n[320x64] + bias (MFMA)
// Round 2: hop kernel rebuilt around async global->LDS staging (m97 form)
// to fix the memory-latency bound (was ~2 TB/s effective; target ~6 TB/s).
// ---------------------------------------------------------------------------

typedef __attribute__((ext_vector_type(4))) float f32x4;
typedef __attribute__((ext_vector_type(2))) float f32x2;
typedef __attribute__((ext_vector_type(8))) short s16x8;
typedef __attribute__((ext_vector_type(8))) __bf16 bf16x8;

__device__ __forceinline__ unsigned short f2bf(float f) {
  union { float f; uint32_t u; } v; v.f = f;
  uint32_t r = v.u + 0x7FFFu + ((v.u >> 16) & 1u);   // RNE
  return (unsigned short)(r >> 16);
}
__device__ __forceinline__ uint32_t pack2(float a, float b) {
  return (uint32_t)f2bf(a) | ((uint32_t)f2bf(b) << 16);
}

union FragU { s16x8 s; bf16x8 b; };

__device__ __forceinline__ void async_cp16(const void* g, void* l) {
  __builtin_amdgcn_global_load_lds(
      (const __attribute__((address_space(1))) void*)g,
      (__attribute__((address_space(3))) void*)l, 16, 0, 0);
}

// ---------------------------------------------------------------------------
// K0a: x [16][1024][64] f32  ->  XT0 [16][64][1024] bf16
// ---------------------------------------------------------------------------
__global__ void transpose_x(const float* __restrict__ x,
                            unsigned short* __restrict__ XT0) {
  __shared__ unsigned short tl[64][72];
  const int b = blockIdx.y, n0 = blockIdx.x * 64;
  const int tid = threadIdx.x;
  {
    const int c4 = (tid & 15) * 4;
#pragma unroll
    for (int i = 0; i < 4; ++i) {
      const int row = (tid >> 4) + i * 16;
      f32x4 v = *(const f32x4*)(x + ((size_t)(b * 1024 + n0 + row)) * 64 + c4);
      *(uint32_t*)&tl[row][c4]     = pack2(v[0], v[1]);
      *(uint32_t*)&tl[row][c4 + 2] = pack2(v[2], v[3]);
    }
  }
  __syncthreads();
  {
    const int c = tid >> 2;
    const int nch = (tid & 3) * 16;
    s16x8 s0, s1;
#pragma unroll
    for (int j = 0; j < 8; ++j) {
      s0[j] = (short)tl[nch + j][c];
      s1[j] = (short)tl[nch + 8 + j][c];
    }
    unsigned short* p = XT0 + (size_t)(b * 64 + c) * 1024 + n0 + nch;
    *(s16x8*)p = s0;
    *(s16x8*)(p + 8) = s1;
  }
}

// ---------------------------------------------------------------------------
// K0b: wp [10][320][64] -> wpT [10][64][320] f32
// ---------------------------------------------------------------------------
__global__ void transpose_wp(const float* __restrict__ wp,
                             float* __restrict__ wpT) {
  __shared__ float tl[64][65];
  const int d = blockIdx.y;
  const int ki0 = blockIdx.x * 64;
  const int tid = threadIdx.x;
  const float* src = wp + (size_t)d * 20480;
  {
    const int o4 = (tid & 15) * 4;
#pragma unroll
    for (int i = 0; i < 4; ++i) {
      const int row = (tid >> 4) + i * 16;
      f32x4 v = *(const f32x4*)(src + (size_t)(ki0 + row) * 64 + o4);
      tl[row][o4] = v[0]; tl[row][o4 + 1] = v[1];
      tl[row][o4 + 2] = v[2]; tl[row][o4 + 3] = v[3];
    }
  }
  __syncthreads();
  {
    const int o = tid >> 2;
    const int kch = (tid & 3) * 16;
    float* dst = wpT + (size_t)d * 20480 + (size_t)o * 320 + ki0 + kch;
#pragma unroll
    for (int u = 0; u < 4; ++u) {
      f32x4 v = { tl[kch + 4 * u][o], tl[kch + 4 * u + 1][o],
                  tl[kch + 4 * u + 2][o], tl[kch + 4 * u + 3][o] };
      *(f32x4*)(dst + 4 * u) = v;
    }
  }
}

// ---------------------------------------------------------------------------
// K4: WT[n][o][ki] bf16 = sum_d emb[n,d] * wpT[d][o][ki]
// grid (40, 64), block 256; 2 ki per thread -> 4 B stores.
// ---------------------------------------------------------------------------
__global__ __launch_bounds__(256) void wgen(const float* __restrict__ wpT,
                                            const float* __restrict__ emb,
                                            unsigned short* __restrict__ WT) {
  const int idx = (blockIdx.x * 256 + threadIdx.x) * 2;   // 0..20478
  const int n0 = blockIdx.y * 16;
  f32x2 wv[10];
#pragma unroll
  for (int d = 0; d < 10; ++d)
    wv[d] = *(const f32x2*)(wpT + (size_t)d * 20480 + idx);
#pragma unroll
  for (int g = 0; g < 16; ++g) {
    float a0 = 0.f, a1 = 0.f;
#pragma unroll
    for (int d = 0; d < 10; ++d) {
      const float e = emb[(n0 + g) * 10 + d];
      a0 += e * wv[d][0];
      a1 += e * wv[d][1];
    }
    *(uint32_t*)(WT + (size_t)(n0 + g) * 20480 + idx) = pack2(a0, a1);
  }
}

// ---------------------------------------------------------------------------
// K2/K3: hop GEMM, m97-style. Per slice: out[1024][64] = A[1024][1024]@X[1024][64]
// Block = 256 thr (4 waves), tile 64 rows x 64 cols, BK=64, double-buffered
// async global->LDS staging for A (fp32) and B (XT bf16). XOR chunk swizzle
// on the *global source* side so the fixed lane->LDS mapping yields a
// bank-balanced tile (<=2-way aliasing on fragment reads).
// grid (16 row-tiles, 32 slices).
// ---------------------------------------------------------------------------
__global__ __launch_bounds__(256, 2) void hop_kernel(
    const float* __restrict__ adj, const unsigned short* __restrict__ XTin,
    float* __restrict__ Xout, unsigned short* __restrict__ XTout,
    int xt_shared, int write_xt) {
  __shared__ __align__(16) char smem[2 * (16384 + 8192)];   // 48 KB
  const int slice = blockIdx.y;          // s*16 + b
  const int b = slice & 15;
  const float* __restrict__ A = adj + (size_t)slice * (1024u * 1024u);
  const unsigned short* __restrict__ XT =
      XTin + (size_t)(xt_shared ? b : slice) * (64 * 1024);
  const int tid = threadIdx.x;
  const int wave = tid >> 6, lane = tid & 63;
  const int l15 = lane & 15, q = lane >> 4;
  const int rowbase = blockIdx.x * 64;

  // A staging: instr i covers tile rows wave*16+i*4 .. +3; lane->16B chunk.
  int arow[4], acol[4];
#pragma unroll
  for (int i = 0; i < 4; ++i) {
    const int r = wave * 16 + i * 4 + (lane >> 4);
    arow[i] = r;
    acol[i] = ((lane & 15) ^ (r & 7)) * 4;     // floats
  }
  // B staging: instr i covers tile cols wave*16+i*8 .. +7.
  int bc[2], bcol[2];
#pragma unroll
  for (int i = 0; i < 2; ++i) {
    const int c = wave * 16 + i * 8 + (lane >> 3);
    bc[i] = c;
    bcol[i] = ((lane & 7) ^ (c & 7)) * 8;      // bf16 elems
  }

  float* const Ab0 = (float*)smem;
  float* const Ab1 = (float*)(smem + 24576);
  unsigned short* const Bb0 = (unsigned short*)(smem + 16384);
  unsigned short* const Bb1 = (unsigned short*)(smem + 24576 + 16384);

  auto issue = [&](int k0, int s) {
    float* Abuf = s ? Ab1 : Ab0;
    unsigned short* Bbuf = s ? Bb1 : Bb0;
#pragma unroll
    for (int i = 0; i < 4; ++i)
      async_cp16(A + (size_t)(rowbase + arow[i]) * 1024 + k0 + acol[i],
                 Abuf + (size_t)(wave * 16 + i * 4) * 64);
#pragma unroll
    for (int i = 0; i < 2; ++i)
      async_cp16(XT + (size_t)bc[i] * 1024 + k0 + bcol[i],
                 Bbuf + (size_t)(wave * 16 + i * 8) * 64);
  };

  f32x4 acc[4];
#pragma unroll
  for (int t = 0; t < 4; ++t) acc[t] = (f32x4){0.f, 0.f, 0.f, 0.f};

  issue(0, 0);
  const int r = wave * 16 + l15;
  const int rx = r & 7;
  for (int kt = 0; kt < 16; ++kt) {
    const int cur = kt & 1;
    __syncthreads();                       // stage kt landed; prev slot free
    if (kt + 1 < 16) issue((kt + 1) * 64, cur ^ 1);
    const float* Abuf = cur ? Ab1 : Ab0;
    const unsigned short* Bbuf = cur ? Bb1 : Bb0;
#pragma unroll
    for (int h = 0; h < 2; ++h) {
      const int j0 = h * 8 + q * 2;
      f32x4 c0 = *(const f32x4*)(Abuf + r * 64 + ((j0) ^ rx) * 4);
      f32x4 c1 = *(const f32x4*)(Abuf + r * 64 + ((j0 + 1) ^ rx) * 4);
      FragU af;
#pragma unroll
      for (int e = 0; e < 4; ++e) {
        af.s[e]     = (short)f2bf(c0[e]);
        af.s[e + 4] = (short)f2bf(c1[e]);
      }
      const int pc = (h * 4 + q) ^ (l15 & 7);
#pragma unroll
      for (int t = 0; t < 4; ++t) {
        FragU bf;
        bf.s = *(const s16x8*)(Bbuf + (t * 16 + l15) * 64 + pc * 8);
        acc[t] = __builtin_amdgcn_mfma_f32_16x16x32_bf16(af.b, bf.b, acc[t],
                                                         0, 0, 0);
      }
    }
  }

  // Epilogue: transpose via LDS (reuse stage memory)
  __syncthreads();
  float (*tile)[65] = (float(*)[65])smem;
#pragma unroll
  for (int t = 0; t < 4; ++t)
#pragma unroll
    for (int rr = 0; rr < 4; ++rr)
      tile[wave * 16 + q * 4 + rr][t * 16 + l15] = acc[t][rr];
  __syncthreads();

  {
    const int row = tid >> 2;
    const int cb = (tid & 3) * 16;
    float* __restrict__ outp = Xout + (size_t)slice * (1024 * 64) +
                               (size_t)(rowbase + row) * 64 + cb;
#pragma unroll
    for (int u = 0; u < 4; ++u) {
      f32x4 v = { tile[row][cb + 4 * u], tile[row][cb + 4 * u + 1],
                  tile[row][cb + 4 * u + 2], tile[row][cb + 4 * u + 3] };
      *(f32x4*)(outp + 4 * u) = v;
    }
  }
  if (write_xt) {
    const int c = tid >> 2;
    const int nch = (tid & 3) * 16;
    unsigned short* __restrict__ xtp = XTout + (size_t)slice * (64 * 1024) +
                                       (size_t)c * 1024 + rowbase + nch;
    s16x8 s0, s1;
#pragma unroll
    for (int j = 0; j < 8; ++j) {
      s0[j] = (short)f2bf(tile[nch + j][c]);
      s1[j] = (short)f2bf(tile[nch + 8 + j][c]);
    }
    *(s16x8*)xtp = s0;
    *(s16x8*)(xtp + 8) = s1;
  }
}

// ---------------------------------------------------------------------------
// K5: out[b,n,o] = Xg[b,n,:] (320) @ W_n[320,64] + bias[n,o]
// One wave per node; Xg staged bf16 in LDS. grid 256, block 256.
// ---------------------------------------------------------------------------
__global__ __launch_bounds__(256, 2) void final_kernel(
    const float* __restrict__ x, const float* __restrict__ X1,
    const float* __restrict__ X2, const unsigned short* __restrict__ WT,
    const float* __restrict__ emb, const float* __restrict__ bias_pool,
    float* __restrict__ out) {
  __shared__ unsigned short xg[4][16][328];
  const int tid = threadIdx.x;
  const int node_base = blockIdx.x * 4;

  for (int u = tid; u < 10240; u += 256) {       // units of 2 ki
    const int nd = u / 2560;
    int rem = u - nd * 2560;
    const int bb = rem / 160;
    const int kiu = rem - bb * 160;
    const int ki = kiu * 2;
    const int k = ki >> 6;
    const int c = ki & 63;
    const int nn = node_base + nd;
    const float* src;
    if (k == 0) {
      src = x + ((size_t)bb * 1024 + nn) * 64 + c;
    } else {
      const float* arr = (k == 1 || k == 3) ? X1 : X2;
      const int s = (k >= 3) ? 1 : 0;
      src = arr + ((size_t)(s * 16 + bb) * 1024 + nn) * 64 + c;
    }
    f32x2 v = *(const f32x2*)src;
    *(uint32_t*)&xg[nd][bb][ki] = pack2(v[0], v[1]);
  }
  __syncthreads();

  const int wave = tid >> 6, lane = tid & 63;
  const int l15 = lane & 15, q = lane >> 4;
  const int n = node_base + wave;
  f32x4 acc[4];
#pragma unroll
  for (int t = 0; t < 4; ++t) acc[t] = (f32x4){0.f, 0.f, 0.f, 0.f};

  const unsigned short* wt0 =
      WT + (size_t)n * 20480 + (size_t)l15 * 320 + q * 8;
#pragma unroll
  for (int ks = 0; ks < 10; ++ks) {
    const int k0 = ks * 32;
    FragU af;
    af.s = *(const s16x8*)&xg[wave][l15][k0 + q * 8];
#pragma unroll
    for (int t = 0; t < 4; ++t) {
      FragU bf;
      bf.s = *(const s16x8*)(wt0 + (size_t)t * (16 * 320) + k0);
      acc[t] = __builtin_amdgcn_mfma_f32_16x16x32_bf16(af.b, bf.b, acc[t],
                                                       0, 0, 0);
    }
  }

#pragma unroll
  for (int t = 0; t < 4; ++t) {
    const int o = t * 16 + l15;
    float bv = 0.f;
#pragma unroll
    for (int d = 0; d < 10; ++d)
      bv += emb[n * 10 + d] * bias_pool[d * 64 + o];
#pragma unroll
    for (int rr = 0; rr < 4; ++rr) {
      const int bb = q * 4 + rr;
      out[((size_t)bb * 1024 + n) * 64 + o] = acc[t][rr] + bv;
    }
  }
}

// ---------------------------------------------------------------------------
extern "C" void kernel_launch(void* const* d_in, const int* in_sizes, int n_in,
                              void* d_out, int out_size, void* d_ws,
                              size_t ws_size, hipStream_t stream) {
  const float* x   = (const float*)d_in[0];   // [16,1024,64]
  const float* adj = (const float*)d_in[1];   // [2,16,1024,1024]
  const float* emb = (const float*)d_in[2];   // [1024,10]
  const float* wp  = (const float*)d_in[3];   // [10,5,64,64]
  const float* bp  = (const float*)d_in[4];   // [10,64]
  float* out = (float*)d_out;                 // [16,1024,64]

  char* ws = (char*)d_ws;
  unsigned short* XT0 = (unsigned short*)(ws);                     // 2 MB
  unsigned short* XT1 = (unsigned short*)(ws + ((size_t)2 << 20)); // 4 MB
  float* X1  = (float*)(ws + ((size_t)6 << 20));                   // 8 MB
  float* X2  = (float*)(ws + ((size_t)14 << 20));                  // 8 MB
  float* wpT = (float*)(ws + ((size_t)22 << 20));                  // 0.82 MB
  unsigned short* WT = (unsigned short*)(ws + ((size_t)23 << 20)); // 40 MB

  transpose_x<<<dim3(16, 16), dim3(256), 0, stream>>>(x, XT0);
  transpose_wp<<<dim3(5, 10), dim3(256), 0, stream>>>(wp, wpT);
  wgen<<<dim3(40, 64), dim3(256), 0, stream>>>(wpT, emb, WT);
  hop_kernel<<<dim3(16, 32), dim3(256), 0, stream>>>(adj, XT0, X1, XT1, 1, 1);
  hop_kernel<<<dim3(16, 32), dim3(256), 0, stream>>>(adj, XT1, X2,
                                                     (unsigned short*)nullptr,
                                                     0, 0);
  final_kernel<<<dim3(256), dim3(256), 0, stream>>>(x, X1, X2, WT, emb, bp,
                                                    out);
}